// Round 14
// baseline (351.053 us; speedup 1.0000x reference)
//
#include <hip/hip_runtime.h>
#include <hip/hip_bf16.h>
#include <math.h>

#define NN 50000
#define NE 800000
#define NB 512
#define FIN 74
#define HD 64
#define BN_EPS 1e-5f

#define CHUNK 32
#define ELLW 48
#define NBLK ((NN + CHUNK - 1) / CHUNK)   // 1563
#define NBUCK2 NBLK                       // bucket == 32-row group
#define EB2 128
#define EPB (NE / EB2)                    // 6250

// ---------------- build (contention-free counting sort by 32-row bucket) ----------------

// per-(edge-block, bucket) LDS histogram; block 0 also does init + layer-0 weight pack
__global__ __launch_bounds__(256) void hist2_kernel(const int* __restrict__ dst,
                                                    int* __restrict__ H,
                                                    float* __restrict__ stats012,
                                                    unsigned long long* __restrict__ zlo,
                                                    unsigned long long* __restrict__ zhi,
                                                    const float* __restrict__ W0,
                                                    const float* __restrict__ rW0,
                                                    float2* __restrict__ Wpk0) {
    __shared__ int lh[NBUCK2];
    int b = blockIdx.x, tid = threadIdx.x;
    for (int i = tid; i < NBUCK2; i += 256) lh[i] = 0;
    __syncthreads();
    int e0 = b * EPB;
    for (int i = tid; i < EPB; i += 256) atomicAdd(&lh[dst[e0 + i] >> 5], 1);
    if (b == 0) {  // fused init (strided; block has 256 threads)
        for (int i = tid; i < 384; i += 256) stats012[i] = 0.f;
        if (tid < 8) { zlo[tid] = 0ull; zhi[tid] = 0ull; }  // zero row NN of both halves
        for (int i = tid; i < FIN * HD; i += 256) Wpk0[i] = make_float2(W0[i], rW0[i]);
    }
    __syncthreads();
    for (int i = tid; i < NBUCK2; i += 256) H[b * NBUCK2 + i] = lh[i];
}

// per bucket: exclusive prefix over the 128 blocks; bucket total -> T
__global__ __launch_bounds__(128) void scanA2_kernel(int* __restrict__ H, int* __restrict__ T) {
    __shared__ int l[128];
    int k = blockIdx.x, tid = threadIdx.x;
    int v = H[tid * NBUCK2 + k];
    l[tid] = v;
    __syncthreads();
    for (int off = 1; off < 128; off <<= 1) {
        int t = (tid >= off) ? l[tid - off] : 0;
        __syncthreads();
        l[tid] += t;
        __syncthreads();
    }
    H[tid * NBUCK2 + k] = l[tid] - v;
    if (tid == 127) T[k] = l[127];
}

// exclusive scan of 1563 bucket totals -> bbase[0..NBUCK2]
__global__ __launch_bounds__(256) void scanB2_kernel(const int* __restrict__ T,
                                                     int* __restrict__ bbase) {
    __shared__ int l[256];
    __shared__ int carry;
    int tid = threadIdx.x;
    if (tid == 0) carry = 0;
    __syncthreads();
    for (int c0 = 0; c0 < NBUCK2; c0 += 256) {
        int v = (c0 + tid < NBUCK2) ? T[c0 + tid] : 0;
        l[tid] = v;
        __syncthreads();
        for (int off = 1; off < 256; off <<= 1) {
            int t = (tid >= off) ? l[tid - off] : 0;
            __syncthreads();
            l[tid] += t;
            __syncthreads();
        }
        if (c0 + tid < NBUCK2) bbase[c0 + tid] = l[tid] - v + carry;
        __syncthreads();
        if (tid == 0) carry += l[255];
        __syncthreads();
    }
    if (tid == 0) bbase[NBUCK2] = carry;  // == NE
}

// scatter edges into bucket-grouped packed words: src | (row&31)<<17.
__global__ __launch_bounds__(256) void scatter2_kernel(const int* __restrict__ src,
                                                       const int* __restrict__ dst,
                                                       const int* __restrict__ H,
                                                       const int* __restrict__ bbase,
                                                       unsigned* __restrict__ pairs) {
    __shared__ int cur[NBUCK2];
    int b = blockIdx.x, tid = threadIdx.x;
    for (int i = tid; i < NBUCK2; i += 256) cur[i] = H[b * NBUCK2 + i] + bbase[i];
    __syncthreads();
    int e0 = b * EPB;
    for (int i = tid; i < EPB; i += 256) {
        int d = dst[e0 + i];
        int s = src[e0 + i];
        int pos = atomicAdd(&cur[d >> 5], 1);
        pairs[pos] = (unsigned)s | ((unsigned)(d & 31) << 17);
    }
}

// one block per bucket: rank via LDS -> padded ELL[NN][48] + deg[NN]. Built ONCE, used 3x.
__global__ __launch_bounds__(256) void ellify_kernel(const unsigned* __restrict__ pairs,
                                                     const int* __restrict__ bbase,
                                                     int* __restrict__ ell,
                                                     int* __restrict__ deg, int n) {
    __shared__ int lcnt[CHUNK];
    int bk = blockIdx.x, tid = threadIdx.x;
    if (tid < CHUNK) lcnt[tid] = 0;
    __syncthreads();
    int beg = bbase[bk], end = bbase[bk + 1];
    int r0 = bk * CHUNK;
    for (int i = beg + tid; i < end; i += 256) {
        unsigned v = pairs[i];
        int rloc = (int)(v >> 17);
        int rk = atomicAdd(&lcnt[rloc], 1);
        if (rk < ELLW) ell[(size_t)(r0 + rloc) * ELLW + rk] = (int)(v & 0x1FFFFu);
    }
    __syncthreads();
    for (int i = tid; i < CHUNK * ELLW; i += 256) {
        int r = i / ELLW, j = i - r * ELLW;
        if (r0 + r < n && j >= lcnt[r]) ell[(size_t)(r0 + r) * ELLW + j] = NN;
    }
    if (tid < CHUNK && r0 + tid < n) {
        int d = lcnt[tid];
        deg[r0 + tid] = (d < ELLW) ? d : ELLW;
    }
}

// ---------------- dense pieces ----------------

// Row-blocked dual GEMM: xw (split lo/hi bf16 half-tables); res = relu(x @ W2 + rb) (bf16).
template <int K>
__global__ __launch_bounds__(256) void gemm_dual_kernel(
    const float* __restrict__ x, const float2* __restrict__ Wpk,
    const float* __restrict__ rb, __hip_bfloat16* __restrict__ xwlo,
    __hip_bfloat16* __restrict__ xwhi, __hip_bfloat16* __restrict__ res, int n) {
    __shared__ float2 sW[K * HD];
    __shared__ float srb[64];
    for (int i = threadIdx.x; i < K * HD; i += 256) sW[i] = Wpk[i];
    if (threadIdx.x < 64) srb[threadIdx.x] = rb[threadIdx.x];
    __syncthreads();
    int wl = threadIdx.x >> 6, lane = threadIdx.x & 63;
    __hip_bfloat16* xw = (lane < 32) ? xwlo : xwhi;
    int cl32 = lane & 31;
    for (int r0 = (blockIdx.x * 4 + wl) * 8; r0 < n; r0 += gridDim.x * 32) {
        float a1[8], a2[8];
#pragma unroll
        for (int r = 0; r < 8; ++r) { a1[r] = 0.f; a2[r] = 0.f; }
#pragma unroll
        for (int c0 = 0; c0 < K; c0 += 64) {
            const int cl = (K - c0 < 64) ? (K - c0) : 64;
            float xv[8];
#pragma unroll
            for (int r = 0; r < 8; ++r) {
                int row = r0 + r;
                xv[r] = (lane < cl && row < n) ? x[(size_t)row * K + c0 + lane] : 0.f;
            }
            for (int j = 0; j < cl; ++j) {
                float2 w = sW[(c0 + j) * HD + lane];
#pragma unroll
                for (int r = 0; r < 8; ++r) {
                    float xb = __uint_as_float(
                        __builtin_amdgcn_readlane(__float_as_uint(xv[r]), j));
                    a1[r] = fmaf(xb, w.x, a1[r]);
                    a2[r] = fmaf(xb, w.y, a2[r]);
                }
            }
        }
#pragma unroll
        for (int r = 0; r < 8; ++r) {
            int row = r0 + r;
            if (row < n) {
                xw[(size_t)row * 32 + cl32] = __float2bfloat16(a1[r]);
                res[(size_t)row * HD + lane] = __float2bfloat16(fmaxf(a2[r] + srb[lane], 0.f));
            }
        }
    }
}

// BN fold for layer l>=1: writes packed (Wp,rWp) float2 + shiftW + rbp
__global__ void fold_kernel(const float* __restrict__ stats, const float* __restrict__ g,
                            const float* __restrict__ be, const float* __restrict__ W,
                            const float* __restrict__ rW, const float* __restrict__ rb,
                            float2* __restrict__ Wpk, float* __restrict__ shiftW,
                            float* __restrict__ rbp) {
    __shared__ float sc[64], sh[64];
    int t = threadIdx.x;
    if (t < 64) {
        float mean = stats[t] / (float)NN;
        float var = stats[64 + t] / (float)NN - mean * mean;
        float scale = g[t] * rsqrtf(var + BN_EPS);
        sc[t] = scale;
        sh[t] = be[t] - mean * scale;
    }
    __syncthreads();
    for (int i = t; i < 64 * 64; i += 256) {
        int k = i >> 6;
        Wpk[i] = make_float2(sc[k] * W[i], sc[k] * rW[i]);
    }
    if (t < 64) {
        float sw = 0.f, srw = 0.f;
        for (int k = 0; k < 64; ++k) {
            sw = fmaf(sh[k], W[k * 64 + t], sw);
            srw = fmaf(sh[k], rW[k * 64 + t], srw);
        }
        shiftW[t] = sw;
        rbp[t] = rb[t] + srw;
    }
}

__device__ __forceinline__ float bf_lo(unsigned int p) { return __uint_as_float(p << 16); }
__device__ __forceinline__ float bf_hi(unsigned int p) { return __uint_as_float(p & 0xffff0000u); }

// 16-slot gather from the L2-resident half-table (idx direct from ELL, L1-broadcast)
#define GATH16(BASE)                                               \
    {                                                              \
        int id[16];                                                \
        _Pragma("unroll") for (int j = 0; j < 16; ++j) id[j] = myIdx[(BASE) + j]; \
        unsigned dd[16];                                           \
        _Pragma("unroll") for (int j = 0; j < 16; ++j)             \
            dd[j] = XWd[(unsigned)id[j] * 16u + (unsigned)c8];     \
        _Pragma("unroll") for (int j = 0; j < 16; ++j) {           \
            a0 += bf_lo(dd[j]);                                    \
            a1 += bf_hi(dd[j]);                                    \
        }                                                          \
    }

// fused aggregation v7: column-half kernel. Gathers from a 3.2 MB half-table
// (fits per-XCD L2). No staging: ELL indices read directly. 16 lanes/row (4-B loads),
// 4 rows in flight, fixed-16 branch-free phases.
template <int PHASE>
__global__ __launch_bounds__(256) void agg_half_kernel(
    const __hip_bfloat16* __restrict__ xwh, const __hip_bfloat16* __restrict__ res,
    const float* __restrict__ b, const float* __restrict__ shiftW,
    const int* __restrict__ ell, const int* __restrict__ deg,
    float* __restrict__ hout, float* __restrict__ stats, int n) {
    __shared__ float lsr[4][16][4];
    int tid = threadIdx.x;
    int wl = tid >> 6, lane = tid & 63;
    int q = lane >> 4, c8 = lane & 15;
    const unsigned* XWd = (const unsigned*)xwh;
    const unsigned* REd = (const unsigned*)res;
    int r0 = blockIdx.x * CHUNK;
    float2 bv = *(const float2*)&b[PHASE * 32 + 2 * c8];
    float2 swv = shiftW ? *(const float2*)&shiftW[PHASE * 32 + 2 * c8]
                        : make_float2(0.f, 0.f);
    float s0 = 0.f, s1 = 0.f, q0 = 0.f, q1 = 0.f;

#pragma unroll
    for (int p = 0; p < 2; ++p) {
        int grow = r0 + wl * 8 + p * 4 + q;
        int growc = (grow < n) ? grow : (n - 1);
        int mylen = (grow < n) ? deg[growc] : 0;
        int kmax = mylen;
        {
            int t = __shfl_xor(kmax, 16, 64);
            kmax = (t > kmax) ? t : kmax;
            t = __shfl_xor(kmax, 32, 64);
            kmax = (t > kmax) ? t : kmax;  // wave-uniform
        }
        const int* myIdx = &ell[(size_t)growc * ELLW];
        unsigned rdw = REd[(unsigned)growc * 32u + (unsigned)(PHASE * 16 + c8)];
        float a0 = 0.f, a1 = 0.f;
        GATH16(0)
        if (kmax > 16) GATH16(16)
        if (kmax > 32) GATH16(32)
        float dg = (float)mylen;
        float h0 = fmaxf(a0 + fmaf(dg, swv.x, bv.x), 0.f) + bf_lo(rdw);
        float h1 = fmaxf(a1 + fmaf(dg, swv.y, bv.y), 0.f) + bf_hi(rdw);
        if (grow < n) {
            *(float2*)&hout[(unsigned)grow * 64u + (unsigned)(PHASE * 32 + 2 * c8)] =
                make_float2(h0, h1);
            s0 += h0; s1 += h1;
            q0 += h0 * h0; q1 += h1 * h1;
        }
    }

    // reduce across the 4 quarters (same c8 -> same columns)
    s0 += __shfl_xor(s0, 16, 64); s0 += __shfl_xor(s0, 32, 64);
    s1 += __shfl_xor(s1, 16, 64); s1 += __shfl_xor(s1, 32, 64);
    q0 += __shfl_xor(q0, 16, 64); q0 += __shfl_xor(q0, 32, 64);
    q1 += __shfl_xor(q1, 16, 64); q1 += __shfl_xor(q1, 32, 64);
    if (q == 0) {
        lsr[wl][c8][0] = s0; lsr[wl][c8][1] = s1;
        lsr[wl][c8][2] = q0; lsr[wl][c8][3] = q1;
    }
    __syncthreads();
    if (tid < 64) {
        int c8i = tid >> 2, comp = tid & 3;
        float v = lsr[0][c8i][comp] + lsr[1][c8i][comp] + lsr[2][c8i][comp] + lsr[3][c8i][comp];
        int col = PHASE * 32 + 2 * c8i + (comp & 1);
        atomicAdd(&stats[((comp >= 2) ? 64 : 0) + col], v);
    }
}

// ---------------- readout ----------------

__global__ void readout_init_kernel(float* __restrict__ hsum, unsigned int* __restrict__ hmax,
                                    const float* __restrict__ stats, const float* __restrict__ g,
                                    const float* __restrict__ be, float* __restrict__ ss) {
    int idx = blockIdx.x * 256 + threadIdx.x;
    if (idx < NB * HD) {
        hsum[idx] = 0.f;
        hmax[idx] = 0x007FFFFFu;  // encoded(-inf)
    }
    if (blockIdx.x == 0 && threadIdx.x < 64) {
        int c = threadIdx.x;
        float mean = stats[c] / (float)NN;
        float var = stats[64 + c] / (float)NN - mean * mean;
        float scale = g[c] * rsqrtf(var + BN_EPS);
        ss[c] = scale;
        ss[64 + c] = be[c] - mean * scale;
    }
}

#define RNODES 16

__device__ __forceinline__ void ro_flush(float* hsum, unsigned int* hmax, int g, int c,
                                         float accS, float accM) {
    atomicAdd(&hsum[g * HD + c], accS);
    unsigned int bits = __float_as_uint(accM);
    unsigned int enc = (bits & 0x80000000u) ? ~bits : (bits | 0x80000000u);
    atomicMax(&hmax[g * HD + c], enc);
}

__global__ __launch_bounds__(256) void readout_kernel(
    const float* __restrict__ h, const int* __restrict__ gid, const float* __restrict__ ss,
    const float* __restrict__ awW, const float* __restrict__ awb, float* __restrict__ hsum,
    unsigned int* __restrict__ hmax, int n) {
    int wid = blockIdx.x * 4 + (threadIdx.x >> 6);
    int c = threadIdx.x & 63;
    int r0 = wid * RNODES;
    if (r0 >= n) return;
    int r1 = r0 + RNODES;
    if (r1 > n) r1 = n;
    float aw = awW[c], ab = awb[0];
    float sA = ss[c], sB = ss[64 + c];
    int cur = gid[r0];
    float accS = 0.f, accM = -__builtin_inff();
    for (int r = r0; r < r1; ++r) {
        int g = gid[r];
        if (g != cur) {
            ro_flush(hsum, hmax, cur, c, accS, accM);
            accS = 0.f;
            accM = -__builtin_inff();
            cur = g;
        }
        float v = fmaf(h[(size_t)r * HD + c], sA, sB);
        float p = v * aw;
        for (int off = 32; off; off >>= 1) p += __shfl_xor(p, off, 64);
        float w = 1.f / (1.f + expf(-(p + ab)));
        accS = fmaf(v, w, accS);
        accM = fmaxf(accM, v);
    }
    ro_flush(hsum, hmax, cur, c, accS, accM);
}

__global__ void final_kernel(const float* __restrict__ hsum, const unsigned int* __restrict__ hmax,
                             const float* __restrict__ outW, const float* __restrict__ outb,
                             float* __restrict__ out) {
    __shared__ float sW[128 * 64];
    for (int i = threadIdx.x; i < 128 * 64; i += 256) sW[i] = outW[i];
    __syncthreads();
    int idx = blockIdx.x * 256 + threadIdx.x;
    if (idx >= NB * HD) return;
    int bi = idx >> 6, o = idx & 63;
    float acc = outb[o];
#pragma unroll 4
    for (int k = 0; k < 64; ++k) acc = fmaf(hsum[bi * 64 + k], sW[k * 64 + o], acc);
#pragma unroll 4
    for (int k = 0; k < 64; ++k) {
        unsigned int e = hmax[bi * 64 + k];
        float m;
        if (e == 0x007FFFFFu) {
            m = 0.f;  // empty graph
        } else {
            m = (e & 0x80000000u) ? __uint_as_float(e ^ 0x80000000u) : __uint_as_float(~e);
        }
        acc = fmaf(m, sW[(64 + k) * 64 + o], acc);
    }
    out[idx] = acc;
}

// ---------------- launch ----------------

extern "C" void kernel_launch(void* const* d_in, const int* in_sizes, int n_in,
                              void* d_out, int out_size, void* d_ws, size_t ws_size,
                              hipStream_t stream) {
    const float* feats = (const float*)d_in[0];
    const int* src = (const int*)d_in[1];
    const int* dst = (const int*)d_in[2];
    const int* gid = (const int*)d_in[3];
    const float* W[3];
    const float* b[3];
    const float* rW[3];
    const float* rb[3];
    const float* g[3];
    const float* be[3];
    for (int l = 0; l < 3; ++l) {
        W[l] = (const float*)d_in[4 + 6 * l + 0];
        b[l] = (const float*)d_in[4 + 6 * l + 1];
        rW[l] = (const float*)d_in[4 + 6 * l + 2];
        rb[l] = (const float*)d_in[4 + 6 * l + 3];
        g[l] = (const float*)d_in[4 + 6 * l + 4];
        be[l] = (const float*)d_in[4 + 6 * l + 5];
    }
    const float* awW = (const float*)d_in[22];
    const float* awb = (const float*)d_in[23];
    const float* outW = (const float*)d_in[24];
    const float* outb = (const float*)d_in[25];
    float* out = (float*)d_out;

    // workspace layout
    __hip_bfloat16* XWlo = (__hip_bfloat16*)d_ws;               // (NN+1)*32 bf16 (row NN zeros)
    __hip_bfloat16* XWhi = XWlo + (size_t)(NN + 1) * 32;        // (NN+1)*32 bf16
    __hip_bfloat16* RES = XWhi + (size_t)(NN + 1) * 32;         // NN*64 bf16
    float* P1 = (float*)(RES + (size_t)NN * HD);                // N*64 f32 (h, in place)
    float* stats = P1 + (size_t)NN * HD;                        // 3*128
    float* ss2 = stats + 384;                                   // 128
    float2* WPK = (float2*)(ss2 + 128);                         // FIN*HD float2
    float* shW = (float*)(WPK + FIN * HD);                      // 64
    float* rbp = shW + 64;                                      // 64
    float* hsum = rbp + 64;                                     // B*64
    unsigned int* hmax = (unsigned int*)(hsum + (size_t)NB * HD);  // B*64
    unsigned* pairs = (unsigned*)(hmax + (size_t)NB * HD);      // NE packed words
    int* H = (int*)(pairs + (size_t)NE);                        // EB2*NBUCK2
    int* T = H + (size_t)EB2 * NBUCK2;                          // NBUCK2
    int* bbase = T + NBUCK2;                                    // NBUCK2+1
    int* ell = bbase + NBUCK2 + 1;                              // NN*ELLW
    int* deg = ell + (size_t)NN * ELLW;                         // NN

    float* stats0 = stats;
    float* stats1 = stats + 128;
    float* stats2 = stats + 256;

    const int GEMMBLK = 1280;
    const int ROBLK = (NN + RNODES * 4 - 1) / (RNODES * 4);

    // ---- build: counting sort -> bucket-grouped pairs -> padded ELL (once) ----
    hist2_kernel<<<EB2, 256, 0, stream>>>(dst, H, stats,
                                          (unsigned long long*)(XWlo + (size_t)NN * 32),
                                          (unsigned long long*)(XWhi + (size_t)NN * 32),
                                          W[0], rW[0], WPK);
    scanA2_kernel<<<NBUCK2, 128, 0, stream>>>(H, T);
    scanB2_kernel<<<1, 256, 0, stream>>>(T, bbase);
    scatter2_kernel<<<EB2, 256, 0, stream>>>(src, dst, H, bbase, pairs);
    ellify_kernel<<<NBUCK2, 256, 0, stream>>>(pairs, bbase, ell, deg, NN);

    // ---- layer 0 ----
    gemm_dual_kernel<FIN><<<GEMMBLK, 256, 0, stream>>>(feats, WPK, rb[0], XWlo, XWhi, RES, NN);
    agg_half_kernel<0><<<NBLK, 256, 0, stream>>>(XWlo, RES, b[0], (const float*)nullptr, ell,
                                                 deg, P1, stats0, NN);
    agg_half_kernel<1><<<NBLK, 256, 0, stream>>>(XWhi, RES, b[0], (const float*)nullptr, ell,
                                                 deg, P1, stats0, NN);

    // ---- layer 1 (fold BN0) ----
    fold_kernel<<<1, 256, 0, stream>>>(stats0, g[0], be[0], W[1], rW[1], rb[1], WPK, shW, rbp);
    gemm_dual_kernel<HD><<<GEMMBLK, 256, 0, stream>>>(P1, WPK, rbp, XWlo, XWhi, RES, NN);
    agg_half_kernel<0><<<NBLK, 256, 0, stream>>>(XWlo, RES, b[1], shW, ell, deg, P1, stats1, NN);
    agg_half_kernel<1><<<NBLK, 256, 0, stream>>>(XWhi, RES, b[1], shW, ell, deg, P1, stats1, NN);

    // ---- layer 2 (fold BN1) ----
    fold_kernel<<<1, 256, 0, stream>>>(stats1, g[1], be[1], W[2], rW[2], rb[2], WPK, shW, rbp);
    gemm_dual_kernel<HD><<<GEMMBLK, 256, 0, stream>>>(P1, WPK, rbp, XWlo, XWhi, RES, NN);
    agg_half_kernel<0><<<NBLK, 256, 0, stream>>>(XWlo, RES, b[2], shW, ell, deg, P1, stats2, NN);
    agg_half_kernel<1><<<NBLK, 256, 0, stream>>>(XWhi, RES, b[2], shW, ell, deg, P1, stats2, NN);

    // ---- readout (BN2 on the fly) ----
    readout_init_kernel<<<(NB * HD + 255) / 256, 256, 0, stream>>>(hsum, hmax, stats2, g[2], be[2], ss2);
    readout_kernel<<<ROBLK, 256, 0, stream>>>(P1, gid, ss2, awW, awb, hsum, hmax, NN);
    final_kernel<<<(NB * HD + 255) / 256, 256, 0, stream>>>(hsum, hmax, outW, outb, out);
}

// Round 15
// 322.185 us; speedup vs baseline: 1.0896x; 1.0896x over previous
//
#include <hip/hip_runtime.h>
#include <hip/hip_bf16.h>
#include <math.h>

#define NN 50000
#define NE 800000
#define NB 512
#define FIN 74
#define HD 64
#define BN_EPS 1e-5f

#define CHUNK 32
#define ELLW 32
#define NBLK ((NN + CHUNK - 1) / CHUNK)   // 1563
#define NBUCK2 NBLK                       // bucket == fused_agg block (32 rows)
#define EB2 128
#define EPB (NE / EB2)                    // 6250
#define OCAPW 96

// ---------------- build (contention-free counting sort by 32-row bucket) ----------------

// per-(edge-block, bucket) LDS histogram; block 0 also does init + layer-0 weight pack
__global__ __launch_bounds__(256) void hist2_kernel(const int* __restrict__ dst,
                                                    int* __restrict__ H,
                                                    float* __restrict__ stats012,
                                                    unsigned long long* __restrict__ xw_zrow,
                                                    const float* __restrict__ W0,
                                                    const float* __restrict__ rW0,
                                                    float2* __restrict__ Wpk0) {
    __shared__ int lh[NBUCK2];
    int b = blockIdx.x, tid = threadIdx.x;
    for (int i = tid; i < NBUCK2; i += 256) lh[i] = 0;
    __syncthreads();
    int e0 = b * EPB;
    for (int i = tid; i < EPB; i += 256) atomicAdd(&lh[dst[e0 + i] >> 5], 1);
    if (b == 0) {  // fused init work (strided: block has 256 threads)
        for (int i = tid; i < 384; i += 256) stats012[i] = 0.f;
        if (tid < 16) xw_zrow[tid] = 0ull;  // XW row NN = 128 B of zeros
        for (int i = tid; i < FIN * HD; i += 256) Wpk0[i] = make_float2(W0[i], rW0[i]);
    }
    __syncthreads();
    for (int i = tid; i < NBUCK2; i += 256) H[b * NBUCK2 + i] = lh[i];
}

// per bucket: exclusive prefix over the 128 blocks; bucket total -> T
__global__ __launch_bounds__(128) void scanA2_kernel(int* __restrict__ H, int* __restrict__ T) {
    __shared__ int l[128];
    int k = blockIdx.x, tid = threadIdx.x;
    int v = H[tid * NBUCK2 + k];
    l[tid] = v;
    __syncthreads();
    for (int off = 1; off < 128; off <<= 1) {
        int t = (tid >= off) ? l[tid - off] : 0;
        __syncthreads();
        l[tid] += t;
        __syncthreads();
    }
    H[tid * NBUCK2 + k] = l[tid] - v;  // exclusive prefix within bucket
    if (tid == 127) T[k] = l[127];
}

// exclusive scan of 1563 bucket totals -> bbase[0..NBUCK2]
__global__ __launch_bounds__(256) void scanB2_kernel(const int* __restrict__ T,
                                                     int* __restrict__ bbase) {
    __shared__ int l[256];
    __shared__ int carry;
    int tid = threadIdx.x;
    if (tid == 0) carry = 0;
    __syncthreads();
    for (int c0 = 0; c0 < NBUCK2; c0 += 256) {
        int v = (c0 + tid < NBUCK2) ? T[c0 + tid] : 0;
        l[tid] = v;
        __syncthreads();
        for (int off = 1; off < 256; off <<= 1) {
            int t = (tid >= off) ? l[tid - off] : 0;
            __syncthreads();
            l[tid] += t;
            __syncthreads();
        }
        if (c0 + tid < NBUCK2) bbase[c0 + tid] = l[tid] - v + carry;
        __syncthreads();
        if (tid == 0) carry += l[255];
        __syncthreads();
    }
    if (tid == 0) bbase[NBUCK2] = carry;  // == NE
}

// scatter edges into bucket-grouped packed words: src | (row&31)<<17.
// cursors = H[b][k] + bbase[k] (addC fused); LDS cursors only, no global atomics.
__global__ __launch_bounds__(256) void scatter2_kernel(const int* __restrict__ src,
                                                       const int* __restrict__ dst,
                                                       const int* __restrict__ H,
                                                       const int* __restrict__ bbase,
                                                       unsigned* __restrict__ pairs) {
    __shared__ int cur[NBUCK2];
    int b = blockIdx.x, tid = threadIdx.x;
    for (int i = tid; i < NBUCK2; i += 256) cur[i] = H[b * NBUCK2 + i] + bbase[i];
    __syncthreads();
    int e0 = b * EPB;
    for (int i = tid; i < EPB; i += 256) {
        int d = dst[e0 + i];
        int s = src[e0 + i];
        int pos = atomicAdd(&cur[d >> 5], 1);
        pairs[pos] = (unsigned)s | ((unsigned)(d & 31) << 17);
    }
}

// ---------------- dense pieces ----------------

// Row-blocked dual GEMM: xw = x @ W1 (bf16); res = relu(x @ W2 + rb) (bf16).
// j-loop unrolled 16-deep -> 16 ds_read_b64 in flight (was serial LDS-latency chain).
template <int K>
__global__ __launch_bounds__(256) void gemm_dual_kernel(
    const float* __restrict__ x, const float2* __restrict__ Wpk,
    const float* __restrict__ rb, __hip_bfloat16* __restrict__ xw,
    __hip_bfloat16* __restrict__ res, int n) {
    __shared__ float2 sW[K * HD];
    __shared__ float srb[64];
    for (int i = threadIdx.x; i < K * HD; i += 256) sW[i] = Wpk[i];
    if (threadIdx.x < 64) srb[threadIdx.x] = rb[threadIdx.x];
    __syncthreads();
    int wl = threadIdx.x >> 6, lane = threadIdx.x & 63;
    for (int r0 = (blockIdx.x * 4 + wl) * 8; r0 < n; r0 += gridDim.x * 32) {
        float a1[8], a2[8];
#pragma unroll
        for (int r = 0; r < 8; ++r) { a1[r] = 0.f; a2[r] = 0.f; }
#pragma unroll
        for (int c0 = 0; c0 < K; c0 += 64) {
            const int cl = (K - c0 < 64) ? (K - c0) : 64;
            float xv[8];
#pragma unroll
            for (int r = 0; r < 8; ++r) {
                int row = r0 + r;
                xv[r] = (lane < cl && row < n) ? x[(size_t)row * K + c0 + lane] : 0.f;
            }
#pragma unroll 16
            for (int j = 0; j < cl; ++j) {
                float2 w = sW[(c0 + j) * HD + lane];
#pragma unroll
                for (int r = 0; r < 8; ++r) {
                    float xb = __uint_as_float(
                        __builtin_amdgcn_readlane(__float_as_uint(xv[r]), j));
                    a1[r] = fmaf(xb, w.x, a1[r]);
                    a2[r] = fmaf(xb, w.y, a2[r]);
                }
            }
        }
#pragma unroll
        for (int r = 0; r < 8; ++r) {
            int row = r0 + r;
            if (row < n) {
                xw[(size_t)row * HD + lane] = __float2bfloat16(a1[r]);
                res[(size_t)row * HD + lane] = __float2bfloat16(fmaxf(a2[r] + srb[lane], 0.f));
            }
        }
    }
}

// BN fold for layer l>=1: writes packed (Wp,rWp) float2 + shiftW + rbp
__global__ void fold_kernel(const float* __restrict__ stats, const float* __restrict__ g,
                            const float* __restrict__ be, const float* __restrict__ W,
                            const float* __restrict__ rW, const float* __restrict__ rb,
                            float2* __restrict__ Wpk, float* __restrict__ shiftW,
                            float* __restrict__ rbp) {
    __shared__ float sc[64], sh[64];
    int t = threadIdx.x;
    if (t < 64) {
        float mean = stats[t] / (float)NN;
        float var = stats[64 + t] / (float)NN - mean * mean;
        float scale = g[t] * rsqrtf(var + BN_EPS);
        sc[t] = scale;
        sh[t] = be[t] - mean * scale;
    }
    __syncthreads();
    for (int i = t; i < 64 * 64; i += 256) {
        int k = i >> 6;
        Wpk[i] = make_float2(sc[k] * W[i], sc[k] * rW[i]);
    }
    if (t < 64) {
        float sw = 0.f, srw = 0.f;
        for (int k = 0; k < 64; ++k) {
            sw = fmaf(sh[k], W[k * 64 + t], sw);
            srw = fmaf(sh[k], rW[k * 64 + t], srw);
        }
        shiftW[t] = sw;
        rbp[t] = rb[t] + srw;
    }
}

__device__ __forceinline__ float bf_lo(unsigned int p) { return __uint_as_float(p << 16); }
__device__ __forceinline__ float bf_hi(unsigned int p) { return __uint_as_float(p & 0xffff0000u); }

// 16-slot branch-free gather batch (pads hit the hot zero row -> L1)
#define GATHER16(BASE)                                             \
    {                                                              \
        unsigned long long d[16];                                  \
        _Pragma("unroll") for (int j = 0; j < 16; ++j) {           \
            int idx = myIdx[(BASE) + j];                           \
            unsigned off = (unsigned)idx * 16u + (unsigned)c8;     \
            d[j] = XWu[off];                                       \
        }                                                          \
        _Pragma("unroll") for (int j = 0; j < 16; ++j) {           \
            unsigned lo = (unsigned)d[j], hi = (unsigned)(d[j] >> 32); \
            a0 += bf_lo(lo); a1 += bf_hi(lo);                      \
            a2 += bf_lo(hi); a3 += bf_hi(hi);                      \
        }                                                          \
    }

// fused aggregation v6: WAVE-LOCAL staging (no staging barrier) from packed pairs;
// 16 lanes/row, 4 rows in flight, fixed-16 branch-free phases; per-wave LDS overflow.
__global__ __launch_bounds__(256, 6) void fused_agg_kernel(
    const __hip_bfloat16* __restrict__ xw, const __hip_bfloat16* __restrict__ res,
    const float* __restrict__ b, const float* __restrict__ shiftW,
    const int* __restrict__ bbase, const unsigned* __restrict__ pairs,
    float* __restrict__ hout, float* __restrict__ stats, int n) {
    __shared__ int sIdx[4][8][ELLW + 1];  // per wave x 8 rows
    __shared__ int sLen[4][8];
    __shared__ unsigned oflow[4][OCAPW];
    __shared__ int ocnt[4];
    __shared__ float lsr[4][16][8];

    int tid = threadIdx.x;
    int wl = tid >> 6, lane = tid & 63;
    int r0 = blockIdx.x * CHUNK;

    // wave-local init (only this wave touches its region; no barrier needed)
    for (int i = lane; i < 8 * (ELLW + 1); i += 64) ((int*)sIdx[wl])[i] = NN;
    if (lane < 8) sLen[wl][lane] = 0;
    if (lane == 0) ocnt[wl] = 0;

    int beg = bbase[blockIdx.x], end = bbase[blockIdx.x + 1];
    // every wave scans the block's pair window, keeps only its own 8 rows
    for (int i = beg + lane; i < end; i += 64) {
        unsigned v = pairs[i];
        int rloc = (int)(v >> 17);
        if ((rloc >> 3) == wl) {
            int r8 = rloc & 7;
            int rk = atomicAdd(&sLen[wl][r8], 1);
            if (rk < ELLW) {
                sIdx[wl][r8][rk] = (int)(v & 0x1FFFFu);
            } else {
                int o = atomicAdd(&ocnt[wl], 1);
                if (o < OCAPW) oflow[wl][o] = v;
            }
        }
    }
    int nof = ocnt[wl];
    int noflow = (nof < OCAPW) ? nof : OCAPW;

    const unsigned long long* XWu = (const unsigned long long*)xw;
    const unsigned long long* REu = (const unsigned long long*)res;
    int q = lane >> 4, c8 = lane & 15;
    // biases straight from global (L2-hot), no LDS / no barrier
    float4 bv = *(const float4*)&b[4 * c8];
    float4 swv = shiftW ? *(const float4*)&shiftW[4 * c8] : make_float4(0.f, 0.f, 0.f, 0.f);
    float s0 = 0.f, s1 = 0.f, s2 = 0.f, s3 = 0.f;
    float q0 = 0.f, q1 = 0.f, q2 = 0.f, q3 = 0.f;

#pragma unroll
    for (int p = 0; p < 2; ++p) {
        int r8 = p * 4 + q;                 // local row within wave
        int grow = r0 + wl * 8 + r8;        // global row
        int growc = (grow < n) ? grow : (n - 1);
        int l0 = sLen[wl][p * 4], l1 = sLen[wl][p * 4 + 1];
        int l2 = sLen[wl][p * 4 + 2], l3 = sLen[wl][p * 4 + 3];
        int m01 = (l0 > l1) ? l0 : l1, m23 = (l2 > l3) ? l2 : l3;
        int kmax = (m01 > m23) ? m01 : m23;  // wave-uniform
        int mylen = sLen[wl][r8];
        const int* myIdx = sIdx[wl][r8];
        unsigned long long rqw = REu[(unsigned)growc * 16u + (unsigned)c8];  // residual early
        float a0 = 0.f, a1 = 0.f, a2 = 0.f, a3 = 0.f;
        GATHER16(0)
        if (kmax > 16) GATHER16(16)
        if (kmax > ELLW) {  // rare: scan this wave's overflow list
            int myrloc = wl * 8 + r8;
            for (int o = 0; o < noflow; ++o) {
                unsigned v = oflow[wl][o];
                if ((int)(v >> 17) == myrloc) {
                    unsigned off = (v & 0x1FFFFu) * 16u + (unsigned)c8;
                    unsigned long long u = XWu[off];
                    unsigned lo = (unsigned)u, hi = (unsigned)(u >> 32);
                    a0 += bf_lo(lo); a1 += bf_hi(lo);
                    a2 += bf_lo(hi); a3 += bf_hi(hi);
                }
            }
        }
        unsigned rlo = (unsigned)rqw, rhi = (unsigned)(rqw >> 32);
        float dg = (float)mylen;
        float h0 = fmaxf(a0 + fmaf(dg, swv.x, bv.x), 0.f) + bf_lo(rlo);
        float h1 = fmaxf(a1 + fmaf(dg, swv.y, bv.y), 0.f) + bf_hi(rlo);
        float h2 = fmaxf(a2 + fmaf(dg, swv.z, bv.z), 0.f) + bf_lo(rhi);
        float h3 = fmaxf(a3 + fmaf(dg, swv.w, bv.w), 0.f) + bf_hi(rhi);
        if (grow < n) {
            *(float4*)&hout[(unsigned)grow * 64u + 4u * c8] = make_float4(h0, h1, h2, h3);
            s0 += h0; s1 += h1; s2 += h2; s3 += h3;
            q0 += h0 * h0; q1 += h1 * h1; q2 += h2 * h2; q3 += h3 * h3;
        }
    }

    // reduce across the 4 quarters of the wave (same c8 -> same columns)
    s0 += __shfl_xor(s0, 16, 64); s0 += __shfl_xor(s0, 32, 64);
    s1 += __shfl_xor(s1, 16, 64); s1 += __shfl_xor(s1, 32, 64);
    s2 += __shfl_xor(s2, 16, 64); s2 += __shfl_xor(s2, 32, 64);
    s3 += __shfl_xor(s3, 16, 64); s3 += __shfl_xor(s3, 32, 64);
    q0 += __shfl_xor(q0, 16, 64); q0 += __shfl_xor(q0, 32, 64);
    q1 += __shfl_xor(q1, 16, 64); q1 += __shfl_xor(q1, 32, 64);
    q2 += __shfl_xor(q2, 16, 64); q2 += __shfl_xor(q2, 32, 64);
    q3 += __shfl_xor(q3, 16, 64); q3 += __shfl_xor(q3, 32, 64);
    if (q == 0) {
        lsr[wl][c8][0] = s0; lsr[wl][c8][1] = s1; lsr[wl][c8][2] = s2; lsr[wl][c8][3] = s3;
        lsr[wl][c8][4] = q0; lsr[wl][c8][5] = q1; lsr[wl][c8][6] = q2; lsr[wl][c8][7] = q3;
    }
    __syncthreads();  // the only block-wide barrier
    if (tid < 64) {
        int c8i = tid >> 2, comp = tid & 3;
        float ssum = lsr[0][c8i][comp] + lsr[1][c8i][comp] + lsr[2][c8i][comp] + lsr[3][c8i][comp];
        float qsum = lsr[0][c8i][4 + comp] + lsr[1][c8i][4 + comp] + lsr[2][c8i][4 + comp] +
                     lsr[3][c8i][4 + comp];
        atomicAdd(&stats[tid], ssum);
        atomicAdd(&stats[64 + tid], qsum);
    }
}

// ---------------- readout ----------------

__global__ void readout_init_kernel(float* __restrict__ hsum, unsigned int* __restrict__ hmax,
                                    const float* __restrict__ stats, const float* __restrict__ g,
                                    const float* __restrict__ be, float* __restrict__ ss) {
    int idx = blockIdx.x * 256 + threadIdx.x;
    if (idx < NB * HD) {
        hsum[idx] = 0.f;
        hmax[idx] = 0x007FFFFFu;  // encoded(-inf)
    }
    if (blockIdx.x == 0 && threadIdx.x < 64) {
        int c = threadIdx.x;
        float mean = stats[c] / (float)NN;
        float var = stats[64 + c] / (float)NN - mean * mean;
        float scale = g[c] * rsqrtf(var + BN_EPS);
        ss[c] = scale;
        ss[64 + c] = be[c] - mean * scale;
    }
}

#define RNODES 16

__device__ __forceinline__ void ro_flush(float* hsum, unsigned int* hmax, int g, int c,
                                         float accS, float accM) {
    atomicAdd(&hsum[g * HD + c], accS);
    unsigned int bits = __float_as_uint(accM);
    unsigned int enc = (bits & 0x80000000u) ? ~bits : (bits | 0x80000000u);
    atomicMax(&hmax[g * HD + c], enc);
}

__global__ __launch_bounds__(256) void readout_kernel(
    const float* __restrict__ h, const int* __restrict__ gid, const float* __restrict__ ss,
    const float* __restrict__ awW, const float* __restrict__ awb, float* __restrict__ hsum,
    unsigned int* __restrict__ hmax, int n) {
    int wid = blockIdx.x * 4 + (threadIdx.x >> 6);
    int c = threadIdx.x & 63;
    int r0 = wid * RNODES;
    if (r0 >= n) return;
    int r1 = r0 + RNODES;
    if (r1 > n) r1 = n;
    float aw = awW[c], ab = awb[0];
    float sA = ss[c], sB = ss[64 + c];
    int cur = gid[r0];
    float accS = 0.f, accM = -__builtin_inff();
    for (int r = r0; r < r1; ++r) {
        int g = gid[r];
        if (g != cur) {
            ro_flush(hsum, hmax, cur, c, accS, accM);
            accS = 0.f;
            accM = -__builtin_inff();
            cur = g;
        }
        float v = fmaf(h[(size_t)r * HD + c], sA, sB);
        float p = v * aw;
        for (int off = 32; off; off >>= 1) p += __shfl_xor(p, off, 64);
        float w = 1.f / (1.f + expf(-(p + ab)));
        accS = fmaf(v, w, accS);
        accM = fmaxf(accM, v);
    }
    ro_flush(hsum, hmax, cur, c, accS, accM);
}

__global__ void final_kernel(const float* __restrict__ hsum, const unsigned int* __restrict__ hmax,
                             const float* __restrict__ outW, const float* __restrict__ outb,
                             float* __restrict__ out) {
    __shared__ float sW[128 * 64];
    for (int i = threadIdx.x; i < 128 * 64; i += 256) sW[i] = outW[i];
    __syncthreads();
    int idx = blockIdx.x * 256 + threadIdx.x;
    if (idx >= NB * HD) return;
    int bi = idx >> 6, o = idx & 63;
    float acc = outb[o];
#pragma unroll 4
    for (int k = 0; k < 64; ++k) acc = fmaf(hsum[bi * 64 + k], sW[k * 64 + o], acc);
#pragma unroll 4
    for (int k = 0; k < 64; ++k) {
        unsigned int e = hmax[bi * 64 + k];
        float m;
        if (e == 0x007FFFFFu) {
            m = 0.f;  // empty graph
        } else {
            m = (e & 0x80000000u) ? __uint_as_float(e ^ 0x80000000u) : __uint_as_float(~e);
        }
        acc = fmaf(m, sW[(64 + k) * 64 + o], acc);
    }
    out[idx] = acc;
}

// ---------------- launch ----------------

extern "C" void kernel_launch(void* const* d_in, const int* in_sizes, int n_in,
                              void* d_out, int out_size, void* d_ws, size_t ws_size,
                              hipStream_t stream) {
    const float* feats = (const float*)d_in[0];
    const int* src = (const int*)d_in[1];
    const int* dst = (const int*)d_in[2];
    const int* gid = (const int*)d_in[3];
    const float* W[3];
    const float* b[3];
    const float* rW[3];
    const float* rb[3];
    const float* g[3];
    const float* be[3];
    for (int l = 0; l < 3; ++l) {
        W[l] = (const float*)d_in[4 + 6 * l + 0];
        b[l] = (const float*)d_in[4 + 6 * l + 1];
        rW[l] = (const float*)d_in[4 + 6 * l + 2];
        rb[l] = (const float*)d_in[4 + 6 * l + 3];
        g[l] = (const float*)d_in[4 + 6 * l + 4];
        be[l] = (const float*)d_in[4 + 6 * l + 5];
    }
    const float* awW = (const float*)d_in[22];
    const float* awb = (const float*)d_in[23];
    const float* outW = (const float*)d_in[24];
    const float* outb = (const float*)d_in[25];
    float* out = (float*)d_out;

    // workspace layout
    __hip_bfloat16* XW = (__hip_bfloat16*)d_ws;                 // (NN+1)*64 bf16 (row NN zeros)
    __hip_bfloat16* RES = XW + (size_t)(NN + 1) * HD;           // NN*64 bf16
    float* P1 = (float*)(RES + (size_t)NN * HD);                // N*64 f32 (h, in place)
    float* stats = P1 + (size_t)NN * HD;                        // 3*128
    float* ss2 = stats + 384;                                   // 128
    float2* WPK = (float2*)(ss2 + 128);                         // FIN*HD float2
    float* shW = (float*)(WPK + FIN * HD);                      // 64
    float* rbp = shW + 64;                                      // 64
    float* hsum = rbp + 64;                                     // B*64
    unsigned int* hmax = (unsigned int*)(hsum + (size_t)NB * HD);  // B*64
    unsigned* pairs = (unsigned*)(hmax + (size_t)NB * HD);      // NE packed words
    int* H = (int*)(pairs + (size_t)NE);                        // EB2*NBUCK2
    int* T = H + (size_t)EB2 * NBUCK2;                          // NBUCK2
    int* bbase = T + NBUCK2;                                    // NBUCK2+1

    float* stats0 = stats;
    float* stats1 = stats + 128;
    float* stats2 = stats + 256;

    const int GEMMBLK = 1280;
    const int ROBLK = (NN + RNODES * 4 - 1) / (RNODES * 4);

    // ---- build: contention-free bucket counting sort (+init/+addC fused) ----
    hist2_kernel<<<EB2, 256, 0, stream>>>(dst, H, stats,
                                          (unsigned long long*)(XW + (size_t)NN * HD),
                                          W[0], rW[0], WPK);
    scanA2_kernel<<<NBUCK2, 128, 0, stream>>>(H, T);
    scanB2_kernel<<<1, 256, 0, stream>>>(T, bbase);
    scatter2_kernel<<<EB2, 256, 0, stream>>>(src, dst, H, bbase, pairs);

    // ---- layer 0 ----
    gemm_dual_kernel<FIN><<<GEMMBLK, 256, 0, stream>>>(feats, WPK, rb[0], XW, RES, NN);
    fused_agg_kernel<<<NBLK, 256, 0, stream>>>(XW, RES, b[0], (const float*)nullptr, bbase,
                                               pairs, P1, stats0, NN);

    // ---- layer 1 (fold BN0) ----
    fold_kernel<<<1, 256, 0, stream>>>(stats0, g[0], be[0], W[1], rW[1], rb[1], WPK, shW, rbp);
    gemm_dual_kernel<HD><<<GEMMBLK, 256, 0, stream>>>(P1, WPK, rbp, XW, RES, NN);
    fused_agg_kernel<<<NBLK, 256, 0, stream>>>(XW, RES, b[1], shW, bbase, pairs, P1, stats1, NN);

    // ---- layer 2 (fold BN1) ----
    fold_kernel<<<1, 256, 0, stream>>>(stats1, g[1], be[1], W[2], rW[2], rb[2], WPK, shW, rbp);
    gemm_dual_kernel<HD><<<GEMMBLK, 256, 0, stream>>>(P1, WPK, rbp, XW, RES, NN);
    fused_agg_kernel<<<NBLK, 256, 0, stream>>>(XW, RES, b[2], shW, bbase, pairs, P1, stats2, NN);

    // ---- readout (BN2 on the fly) ----
    readout_init_kernel<<<(NB * HD + 255) / 256, 256, 0, stream>>>(hsum, hmax, stats2, g[2], be[2], ss2);
    readout_kernel<<<ROBLK, 256, 0, stream>>>(P1, gid, ss2, awW, awb, hsum, hmax, NN);
    final_kernel<<<(NB * HD + 255) / 256, 256, 0, stream>>>(hsum, hmax, outW, outb, out);
}

// Round 16
// 321.149 us; speedup vs baseline: 1.0931x; 1.0032x over previous
//
#include <hip/hip_runtime.h>
#include <hip/hip_bf16.h>
#include <math.h>

#define NN 50000
#define NE 800000
#define NB 512
#define FIN 74
#define HD 64
#define BN_EPS 1e-5f

#define CHUNK 32
#define ELLW 32
#define NBLK ((NN + CHUNK - 1) / CHUNK)   // 1563
#define NBUCK2 NBLK                       // bucket == fused_agg block (32 rows)
#define EB2 256
#define EPB (NE / EB2)                    // 3125
#define OCAPW 96

// ---------------- build (contention-free counting sort by 32-row bucket) ----------------

// per-(edge-block, bucket) LDS histogram; block 0 also does init + layer-0 weight pack
__global__ __launch_bounds__(256) void hist2_kernel(const int* __restrict__ dst,
                                                    int* __restrict__ H,
                                                    float* __restrict__ stats012,
                                                    unsigned long long* __restrict__ xw_zrow,
                                                    const float* __restrict__ W0,
                                                    const float* __restrict__ rW0,
                                                    float2* __restrict__ Wpk0) {
    __shared__ int lh[NBUCK2];
    int b = blockIdx.x, tid = threadIdx.x;
    for (int i = tid; i < NBUCK2; i += 256) lh[i] = 0;
    __syncthreads();
    int e0 = b * EPB;
    for (int i = tid; i < EPB; i += 256) atomicAdd(&lh[dst[e0 + i] >> 5], 1);
    if (b == 0) {  // fused init work (strided: block has 256 threads)
        for (int i = tid; i < 384; i += 256) stats012[i] = 0.f;
        if (tid < 16) xw_zrow[tid] = 0ull;  // XW row NN = 128 B of zeros
        for (int i = tid; i < FIN * HD; i += 256) Wpk0[i] = make_float2(W0[i], rW0[i]);
    }
    __syncthreads();
    for (int i = tid; i < NBUCK2; i += 256) H[b * NBUCK2 + i] = lh[i];
}

// per bucket: exclusive prefix over the EB2 blocks; bucket total -> T
__global__ __launch_bounds__(EB2) void scanA2_kernel(int* __restrict__ H, int* __restrict__ T) {
    __shared__ int l[EB2];
    int k = blockIdx.x, tid = threadIdx.x;
    int v = H[tid * NBUCK2 + k];
    l[tid] = v;
    __syncthreads();
    for (int off = 1; off < EB2; off <<= 1) {
        int t = (tid >= off) ? l[tid - off] : 0;
        __syncthreads();
        l[tid] += t;
        __syncthreads();
    }
    H[tid * NBUCK2 + k] = l[tid] - v;  // exclusive prefix within bucket
    if (tid == EB2 - 1) T[k] = l[EB2 - 1];
}

// exclusive scan of 1563 bucket totals -> bbase[0..NBUCK2]
__global__ __launch_bounds__(256) void scanB2_kernel(const int* __restrict__ T,
                                                     int* __restrict__ bbase) {
    __shared__ int l[256];
    __shared__ int carry;
    int tid = threadIdx.x;
    if (tid == 0) carry = 0;
    __syncthreads();
    for (int c0 = 0; c0 < NBUCK2; c0 += 256) {
        int v = (c0 + tid < NBUCK2) ? T[c0 + tid] : 0;
        l[tid] = v;
        __syncthreads();
        for (int off = 1; off < 256; off <<= 1) {
            int t = (tid >= off) ? l[tid - off] : 0;
            __syncthreads();
            l[tid] += t;
            __syncthreads();
        }
        if (c0 + tid < NBUCK2) bbase[c0 + tid] = l[tid] - v + carry;
        __syncthreads();
        if (tid == 0) carry += l[255];
        __syncthreads();
    }
    if (tid == 0) bbase[NBUCK2] = carry;  // == NE
}

// scatter edges into bucket-grouped packed words: src | (row&31)<<17.
// cursors = H[b][k] + bbase[k]; LDS cursors only, no global atomics.
__global__ __launch_bounds__(256) void scatter2_kernel(const int* __restrict__ src,
                                                       const int* __restrict__ dst,
                                                       const int* __restrict__ H,
                                                       const int* __restrict__ bbase,
                                                       unsigned* __restrict__ pairs) {
    __shared__ int cur[NBUCK2];
    int b = blockIdx.x, tid = threadIdx.x;
    for (int i = tid; i < NBUCK2; i += 256) cur[i] = H[b * NBUCK2 + i] + bbase[i];
    __syncthreads();
    int e0 = b * EPB;
    for (int i = tid; i < EPB; i += 256) {
        int d = dst[e0 + i];
        int s = src[e0 + i];
        int pos = atomicAdd(&cur[d >> 5], 1);
        pairs[pos] = (unsigned)s | ((unsigned)(d & 31) << 17);
    }
}

// ---------------- dense pieces ----------------

// Row-blocked dual GEMM: xw = x @ W1 (bf16); res = relu(x @ W2 + rb) (bf16).
// GEMMBLK=1563 -> exactly one 32-row chunk per block (was 2x imbalanced at 1280).
template <int K>
__global__ __launch_bounds__(256) void gemm_dual_kernel(
    const float* __restrict__ x, const float2* __restrict__ Wpk,
    const float* __restrict__ rb, __hip_bfloat16* __restrict__ xw,
    __hip_bfloat16* __restrict__ res, int n) {
    __shared__ float2 sW[K * HD];
    __shared__ float srb[64];
    for (int i = threadIdx.x; i < K * HD; i += 256) sW[i] = Wpk[i];
    if (threadIdx.x < 64) srb[threadIdx.x] = rb[threadIdx.x];
    __syncthreads();
    int wl = threadIdx.x >> 6, lane = threadIdx.x & 63;
    for (int r0 = (blockIdx.x * 4 + wl) * 8; r0 < n; r0 += gridDim.x * 32) {
        float a1[8], a2[8];
#pragma unroll
        for (int r = 0; r < 8; ++r) { a1[r] = 0.f; a2[r] = 0.f; }
#pragma unroll
        for (int c0 = 0; c0 < K; c0 += 64) {
            const int cl = (K - c0 < 64) ? (K - c0) : 64;
            float xv[8];
#pragma unroll
            for (int r = 0; r < 8; ++r) {
                int row = r0 + r;
                xv[r] = (lane < cl && row < n) ? x[(size_t)row * K + c0 + lane] : 0.f;
            }
#pragma unroll 16
            for (int j = 0; j < cl; ++j) {
                float2 w = sW[(c0 + j) * HD + lane];
#pragma unroll
                for (int r = 0; r < 8; ++r) {
                    float xb = __uint_as_float(
                        __builtin_amdgcn_readlane(__float_as_uint(xv[r]), j));
                    a1[r] = fmaf(xb, w.x, a1[r]);
                    a2[r] = fmaf(xb, w.y, a2[r]);
                }
            }
        }
#pragma unroll
        for (int r = 0; r < 8; ++r) {
            int row = r0 + r;
            if (row < n) {
                xw[(size_t)row * HD + lane] = __float2bfloat16(a1[r]);
                res[(size_t)row * HD + lane] = __float2bfloat16(fmaxf(a2[r] + srb[lane], 0.f));
            }
        }
    }
}

// BN fold for layer l>=1: writes packed (Wp,rWp) float2 + shiftW + rbp
__global__ void fold_kernel(const float* __restrict__ stats, const float* __restrict__ g,
                            const float* __restrict__ be, const float* __restrict__ W,
                            const float* __restrict__ rW, const float* __restrict__ rb,
                            float2* __restrict__ Wpk, float* __restrict__ shiftW,
                            float* __restrict__ rbp) {
    __shared__ float sc[64], sh[64];
    int t = threadIdx.x;
    if (t < 64) {
        float mean = stats[t] / (float)NN;
        float var = stats[64 + t] / (float)NN - mean * mean;
        float scale = g[t] * rsqrtf(var + BN_EPS);
        sc[t] = scale;
        sh[t] = be[t] - mean * scale;
    }
    __syncthreads();
    for (int i = t; i < 64 * 64; i += 256) {
        int k = i >> 6;
        Wpk[i] = make_float2(sc[k] * W[i], sc[k] * rW[i]);
    }
    if (t < 64) {
        float sw = 0.f, srw = 0.f;
        for (int k = 0; k < 64; ++k) {
            sw = fmaf(sh[k], W[k * 64 + t], sw);
            srw = fmaf(sh[k], rW[k * 64 + t], srw);
        }
        shiftW[t] = sw;
        rbp[t] = rb[t] + srw;
    }
}

__device__ __forceinline__ float bf_lo(unsigned int p) { return __uint_as_float(p << 16); }
__device__ __forceinline__ float bf_hi(unsigned int p) { return __uint_as_float(p & 0xffff0000u); }

// fused aggregation v7: wave-local staging; DUAL-ROW pipelined gather — both row-groups'
// first-16 batches (32 loads) + both residuals issued before any consume.
__global__ __launch_bounds__(256, 4) void fused_agg_kernel(
    const __hip_bfloat16* __restrict__ xw, const __hip_bfloat16* __restrict__ res,
    const float* __restrict__ b, const float* __restrict__ shiftW,
    const int* __restrict__ bbase, const unsigned* __restrict__ pairs,
    float* __restrict__ hout, float* __restrict__ stats, int n) {
    __shared__ int sIdx[4][8][ELLW + 1];  // per wave x 8 rows
    __shared__ int sLen[4][8];
    __shared__ unsigned oflow[4][OCAPW];
    __shared__ int ocnt[4];
    __shared__ float lsr[4][16][8];

    int tid = threadIdx.x;
    int wl = tid >> 6, lane = tid & 63;
    int r0 = blockIdx.x * CHUNK;

    // wave-local init (only this wave touches its region; no barrier needed)
    for (int i = lane; i < 8 * (ELLW + 1); i += 64) ((int*)sIdx[wl])[i] = NN;
    if (lane < 8) sLen[wl][lane] = 0;
    if (lane == 0) ocnt[wl] = 0;

    int beg = bbase[blockIdx.x], end = bbase[blockIdx.x + 1];
    for (int i = beg + lane; i < end; i += 64) {
        unsigned v = pairs[i];
        int rloc = (int)(v >> 17);
        if ((rloc >> 3) == wl) {
            int r8 = rloc & 7;
            int rk = atomicAdd(&sLen[wl][r8], 1);
            if (rk < ELLW) {
                sIdx[wl][r8][rk] = (int)(v & 0x1FFFFu);
            } else {
                int o = atomicAdd(&ocnt[wl], 1);
                if (o < OCAPW) oflow[wl][o] = v;
            }
        }
    }
    int nof = ocnt[wl];
    int noflow = (nof < OCAPW) ? nof : OCAPW;

    const unsigned long long* XWu = (const unsigned long long*)xw;
    const unsigned long long* REu = (const unsigned long long*)res;
    int q = lane >> 4, c8 = lane & 15;
    float4 bv = *(const float4*)&b[4 * c8];
    float4 swv = shiftW ? *(const float4*)&shiftW[4 * c8] : make_float4(0.f, 0.f, 0.f, 0.f);
    float s0 = 0.f, s1 = 0.f, s2 = 0.f, s3 = 0.f;
    float q0 = 0.f, q1 = 0.f, q2 = 0.f, q3 = 0.f;

    int r8a = q, r8b = 4 + q;
    int growa = r0 + wl * 8 + r8a;
    int growb = r0 + wl * 8 + r8b;
    int growca = (growa < n) ? growa : (n - 1);
    int growcb = (growb < n) ? growb : (n - 1);
    int la0 = sLen[wl][0], la1 = sLen[wl][1], la2 = sLen[wl][2], la3 = sLen[wl][3];
    int lb0 = sLen[wl][4], lb1 = sLen[wl][5], lb2 = sLen[wl][6], lb3 = sLen[wl][7];
    int mA01 = (la0 > la1) ? la0 : la1, mA23 = (la2 > la3) ? la2 : la3;
    int kmaxA = (mA01 > mA23) ? mA01 : mA23;  // wave-uniform
    int mB01 = (lb0 > lb1) ? lb0 : lb1, mB23 = (lb2 > lb3) ? lb2 : lb3;
    int kmaxB = (mB01 > mB23) ? mB01 : mB23;  // wave-uniform
    int lenA = sLen[wl][r8a], lenB = sLen[wl][r8b];
    const int* idxA = sIdx[wl][r8a];
    const int* idxB = sIdx[wl][r8b];

    // ---- issue phase: 32 gather loads + 2 residual loads, all before any consume ----
    unsigned long long dA[16], dB[16];
#pragma unroll
    for (int j = 0; j < 16; ++j) dA[j] = XWu[(unsigned)idxA[j] * 16u + (unsigned)c8];
#pragma unroll
    for (int j = 0; j < 16; ++j) dB[j] = XWu[(unsigned)idxB[j] * 16u + (unsigned)c8];
    unsigned long long rqwA = REu[(unsigned)growca * 16u + (unsigned)c8];
    unsigned long long rqwB = REu[(unsigned)growcb * 16u + (unsigned)c8];

    // ---- consume A ----
    {
        float a0 = 0.f, a1 = 0.f, a2 = 0.f, a3 = 0.f;
#pragma unroll
        for (int j = 0; j < 16; ++j) {
            unsigned lo = (unsigned)dA[j], hi = (unsigned)(dA[j] >> 32);
            a0 += bf_lo(lo); a1 += bf_hi(lo);
            a2 += bf_lo(hi); a3 += bf_hi(hi);
        }
        if (kmaxA > 16) {
            unsigned long long d2[16];
#pragma unroll
            for (int j = 0; j < 16; ++j) d2[j] = XWu[(unsigned)idxA[16 + j] * 16u + (unsigned)c8];
#pragma unroll
            for (int j = 0; j < 16; ++j) {
                unsigned lo = (unsigned)d2[j], hi = (unsigned)(d2[j] >> 32);
                a0 += bf_lo(lo); a1 += bf_hi(lo);
                a2 += bf_lo(hi); a3 += bf_hi(hi);
            }
        }
        if (kmaxA > ELLW) {  // rare: overflow list
            int myrloc = wl * 8 + r8a;
            for (int o = 0; o < noflow; ++o) {
                unsigned v = oflow[wl][o];
                if ((int)(v >> 17) == myrloc) {
                    unsigned long long u = XWu[(v & 0x1FFFFu) * 16u + (unsigned)c8];
                    unsigned lo = (unsigned)u, hi = (unsigned)(u >> 32);
                    a0 += bf_lo(lo); a1 += bf_hi(lo);
                    a2 += bf_lo(hi); a3 += bf_hi(hi);
                }
            }
        }
        unsigned rlo = (unsigned)rqwA, rhi = (unsigned)(rqwA >> 32);
        float dg = (float)lenA;
        float h0 = fmaxf(a0 + fmaf(dg, swv.x, bv.x), 0.f) + bf_lo(rlo);
        float h1 = fmaxf(a1 + fmaf(dg, swv.y, bv.y), 0.f) + bf_hi(rlo);
        float h2 = fmaxf(a2 + fmaf(dg, swv.z, bv.z), 0.f) + bf_lo(rhi);
        float h3 = fmaxf(a3 + fmaf(dg, swv.w, bv.w), 0.f) + bf_hi(rhi);
        if (growa < n) {
            *(float4*)&hout[(unsigned)growa * 64u + 4u * c8] = make_float4(h0, h1, h2, h3);
            s0 += h0; s1 += h1; s2 += h2; s3 += h3;
            q0 += h0 * h0; q1 += h1 * h1; q2 += h2 * h2; q3 += h3 * h3;
        }
    }

    // ---- consume B ----
    {
        float a0 = 0.f, a1 = 0.f, a2 = 0.f, a3 = 0.f;
#pragma unroll
        for (int j = 0; j < 16; ++j) {
            unsigned lo = (unsigned)dB[j], hi = (unsigned)(dB[j] >> 32);
            a0 += bf_lo(lo); a1 += bf_hi(lo);
            a2 += bf_lo(hi); a3 += bf_hi(hi);
        }
        if (kmaxB > 16) {
            unsigned long long d2[16];
#pragma unroll
            for (int j = 0; j < 16; ++j) d2[j] = XWu[(unsigned)idxB[16 + j] * 16u + (unsigned)c8];
#pragma unroll
            for (int j = 0; j < 16; ++j) {
                unsigned lo = (unsigned)d2[j], hi = (unsigned)(d2[j] >> 32);
                a0 += bf_lo(lo); a1 += bf_hi(lo);
                a2 += bf_lo(hi); a3 += bf_hi(hi);
            }
        }
        if (kmaxB > ELLW) {
            int myrloc = wl * 8 + r8b;
            for (int o = 0; o < noflow; ++o) {
                unsigned v = oflow[wl][o];
                if ((int)(v >> 17) == myrloc) {
                    unsigned long long u = XWu[(v & 0x1FFFFu) * 16u + (unsigned)c8];
                    unsigned lo = (unsigned)u, hi = (unsigned)(u >> 32);
                    a0 += bf_lo(lo); a1 += bf_hi(lo);
                    a2 += bf_lo(hi); a3 += bf_hi(hi);
                }
            }
        }
        unsigned rlo = (unsigned)rqwB, rhi = (unsigned)(rqwB >> 32);
        float dg = (float)lenB;
        float h0 = fmaxf(a0 + fmaf(dg, swv.x, bv.x), 0.f) + bf_lo(rlo);
        float h1 = fmaxf(a1 + fmaf(dg, swv.y, bv.y), 0.f) + bf_hi(rlo);
        float h2 = fmaxf(a2 + fmaf(dg, swv.z, bv.z), 0.f) + bf_lo(rhi);
        float h3 = fmaxf(a3 + fmaf(dg, swv.w, bv.w), 0.f) + bf_hi(rhi);
        if (growb < n) {
            *(float4*)&hout[(unsigned)growb * 64u + 4u * c8] = make_float4(h0, h1, h2, h3);
            s0 += h0; s1 += h1; s2 += h2; s3 += h3;
            q0 += h0 * h0; q1 += h1 * h1; q2 += h2 * h2; q3 += h3 * h3;
        }
    }

    // reduce across the 4 quarters of the wave (same c8 -> same columns)
    s0 += __shfl_xor(s0, 16, 64); s0 += __shfl_xor(s0, 32, 64);
    s1 += __shfl_xor(s1, 16, 64); s1 += __shfl_xor(s1, 32, 64);
    s2 += __shfl_xor(s2, 16, 64); s2 += __shfl_xor(s2, 32, 64);
    s3 += __shfl_xor(s3, 16, 64); s3 += __shfl_xor(s3, 32, 64);
    q0 += __shfl_xor(q0, 16, 64); q0 += __shfl_xor(q0, 32, 64);
    q1 += __shfl_xor(q1, 16, 64); q1 += __shfl_xor(q1, 32, 64);
    q2 += __shfl_xor(q2, 16, 64); q2 += __shfl_xor(q2, 32, 64);
    q3 += __shfl_xor(q3, 16, 64); q3 += __shfl_xor(q3, 32, 64);
    if (q == 0) {
        lsr[wl][c8][0] = s0; lsr[wl][c8][1] = s1; lsr[wl][c8][2] = s2; lsr[wl][c8][3] = s3;
        lsr[wl][c8][4] = q0; lsr[wl][c8][5] = q1; lsr[wl][c8][6] = q2; lsr[wl][c8][7] = q3;
    }
    __syncthreads();  // the only block-wide barrier
    if (tid < 64) {
        int c8i = tid >> 2, comp = tid & 3;
        float ssum = lsr[0][c8i][comp] + lsr[1][c8i][comp] + lsr[2][c8i][comp] + lsr[3][c8i][comp];
        float qsum = lsr[0][c8i][4 + comp] + lsr[1][c8i][4 + comp] + lsr[2][c8i][4 + comp] +
                     lsr[3][c8i][4 + comp];
        atomicAdd(&stats[tid], ssum);
        atomicAdd(&stats[64 + tid], qsum);
    }
}

// ---------------- readout ----------------

__global__ void readout_init_kernel(float* __restrict__ hsum, unsigned int* __restrict__ hmax,
                                    const float* __restrict__ stats, const float* __restrict__ g,
                                    const float* __restrict__ be, float* __restrict__ ss) {
    int idx = blockIdx.x * 256 + threadIdx.x;
    if (idx < NB * HD) {
        hsum[idx] = 0.f;
        hmax[idx] = 0x007FFFFFu;  // encoded(-inf)
    }
    if (blockIdx.x == 0 && threadIdx.x < 64) {
        int c = threadIdx.x;
        float mean = stats[c] / (float)NN;
        float var = stats[64 + c] / (float)NN - mean * mean;
        float scale = g[c] * rsqrtf(var + BN_EPS);
        ss[c] = scale;
        ss[64 + c] = be[c] - mean * scale;
    }
}

#define RNODES 16

__device__ __forceinline__ void ro_flush(float* hsum, unsigned int* hmax, int g, int c,
                                         float accS, float accM) {
    atomicAdd(&hsum[g * HD + c], accS);
    unsigned int bits = __float_as_uint(accM);
    unsigned int enc = (bits & 0x80000000u) ? ~bits : (bits | 0x80000000u);
    atomicMax(&hmax[g * HD + c], enc);
}

__global__ __launch_bounds__(256) void readout_kernel(
    const float* __restrict__ h, const int* __restrict__ gid, const float* __restrict__ ss,
    const float* __restrict__ awW, const float* __restrict__ awb, float* __restrict__ hsum,
    unsigned int* __restrict__ hmax, int n) {
    int wid = blockIdx.x * 4 + (threadIdx.x >> 6);
    int c = threadIdx.x & 63;
    int r0 = wid * RNODES;
    if (r0 >= n) return;
    int r1 = r0 + RNODES;
    if (r1 > n) r1 = n;
    float aw = awW[c], ab = awb[0];
    float sA = ss[c], sB = ss[64 + c];
    int cur = gid[r0];
    float accS = 0.f, accM = -__builtin_inff();
    for (int r = r0; r < r1; ++r) {
        int g = gid[r];
        if (g != cur) {
            ro_flush(hsum, hmax, cur, c, accS, accM);
            accS = 0.f;
            accM = -__builtin_inff();
            cur = g;
        }
        float v = fmaf(h[(size_t)r * HD + c], sA, sB);
        float p = v * aw;
        for (int off = 32; off; off >>= 1) p += __shfl_xor(p, off, 64);
        float w = 1.f / (1.f + expf(-(p + ab)));
        accS = fmaf(v, w, accS);
        accM = fmaxf(accM, v);
    }
    ro_flush(hsum, hmax, cur, c, accS, accM);
}

__global__ void final_kernel(const float* __restrict__ hsum, const unsigned int* __restrict__ hmax,
                             const float* __restrict__ outW, const float* __restrict__ outb,
                             float* __restrict__ out) {
    __shared__ float sW[128 * 64];
    for (int i = threadIdx.x; i < 128 * 64; i += 256) sW[i] = outW[i];
    __syncthreads();
    int idx = blockIdx.x * 256 + threadIdx.x;
    if (idx >= NB * HD) return;
    int bi = idx >> 6, o = idx & 63;
    float acc = outb[o];
#pragma unroll 4
    for (int k = 0; k < 64; ++k) acc = fmaf(hsum[bi * 64 + k], sW[k * 64 + o], acc);
#pragma unroll 4
    for (int k = 0; k < 64; ++k) {
        unsigned int e = hmax[bi * 64 + k];
        float m;
        if (e == 0x007FFFFFu) {
            m = 0.f;  // empty graph
        } else {
            m = (e & 0x80000000u) ? __uint_as_float(e ^ 0x80000000u) : __uint_as_float(~e);
        }
        acc = fmaf(m, sW[(64 + k) * 64 + o], acc);
    }
    out[idx] = acc;
}

// ---------------- launch ----------------

extern "C" void kernel_launch(void* const* d_in, const int* in_sizes, int n_in,
                              void* d_out, int out_size, void* d_ws, size_t ws_size,
                              hipStream_t stream) {
    const float* feats = (const float*)d_in[0];
    const int* src = (const int*)d_in[1];
    const int* dst = (const int*)d_in[2];
    const int* gid = (const int*)d_in[3];
    const float* W[3];
    const float* b[3];
    const float* rW[3];
    const float* rb[3];
    const float* g[3];
    const float* be[3];
    for (int l = 0; l < 3; ++l) {
        W[l] = (const float*)d_in[4 + 6 * l + 0];
        b[l] = (const float*)d_in[4 + 6 * l + 1];
        rW[l] = (const float*)d_in[4 + 6 * l + 2];
        rb[l] = (const float*)d_in[4 + 6 * l + 3];
        g[l] = (const float*)d_in[4 + 6 * l + 4];
        be[l] = (const float*)d_in[4 + 6 * l + 5];
    }
    const float* awW = (const float*)d_in[22];
    const float* awb = (const float*)d_in[23];
    const float* outW = (const float*)d_in[24];
    const float* outb = (const float*)d_in[25];
    float* out = (float*)d_out;

    // workspace layout
    __hip_bfloat16* XW = (__hip_bfloat16*)d_ws;                 // (NN+1)*64 bf16 (row NN zeros)
    __hip_bfloat16* RES = XW + (size_t)(NN + 1) * HD;           // NN*64 bf16
    float* P1 = (float*)(RES + (size_t)NN * HD);                // N*64 f32 (h, in place)
    float* stats = P1 + (size_t)NN * HD;                        // 3*128
    float* ss2 = stats + 384;                                   // 128
    float2* WPK = (float2*)(ss2 + 128);                         // FIN*HD float2
    float* shW = (float*)(WPK + FIN * HD);                      // 64
    float* rbp = shW + 64;                                      // 64
    float* hsum = rbp + 64;                                     // B*64
    unsigned int* hmax = (unsigned int*)(hsum + (size_t)NB * HD);  // B*64
    unsigned* pairs = (unsigned*)(hmax + (size_t)NB * HD);      // NE packed words
    int* H = (int*)(pairs + (size_t)NE);                        // EB2*NBUCK2
    int* T = H + (size_t)EB2 * NBUCK2;                          // NBUCK2
    int* bbase = T + NBUCK2;                                    // NBUCK2+1

    float* stats0 = stats;
    float* stats1 = stats + 128;
    float* stats2 = stats + 256;

    const int GEMMBLK = 1563;  // exactly one 32-row chunk per block
    const int ROBLK = (NN + RNODES * 4 - 1) / (RNODES * 4);

    // ---- build: contention-free bucket counting sort ----
    hist2_kernel<<<EB2, 256, 0, stream>>>(dst, H, stats,
                                          (unsigned long long*)(XW + (size_t)NN * HD),
                                          W[0], rW[0], WPK);
    scanA2_kernel<<<NBUCK2, EB2, 0, stream>>>(H, T);
    scanB2_kernel<<<1, 256, 0, stream>>>(T, bbase);
    scatter2_kernel<<<EB2, 256, 0, stream>>>(src, dst, H, bbase, pairs);

    // ---- layer 0 ----
    gemm_dual_kernel<FIN><<<GEMMBLK, 256, 0, stream>>>(feats, WPK, rb[0], XW, RES, NN);
    fused_agg_kernel<<<NBLK, 256, 0, stream>>>(XW, RES, b[0], (const float*)nullptr, bbase,
                                               pairs, P1, stats0, NN);

    // ---- layer 1 (fold BN0) ----
    fold_kernel<<<1, 256, 0, stream>>>(stats0, g[0], be[0], W[1], rW[1], rb[1], WPK, shW, rbp);
    gemm_dual_kernel<HD><<<GEMMBLK, 256, 0, stream>>>(P1, WPK, rbp, XW, RES, NN);
    fused_agg_kernel<<<NBLK, 256, 0, stream>>>(XW, RES, b[1], shW, bbase, pairs, P1, stats1, NN);

    // ---- layer 2 (fold BN1) ----
    fold_kernel<<<1, 256, 0, stream>>>(stats1, g[1], be[1], W[2], rW[2], rb[2], WPK, shW, rbp);
    gemm_dual_kernel<HD><<<GEMMBLK, 256, 0, stream>>>(P1, WPK, rbp, XW, RES, NN);
    fused_agg_kernel<<<NBLK, 256, 0, stream>>>(XW, RES, b[2], shW, bbase, pairs, P1, stats2, NN);

    // ---- readout (BN2 on the fly) ----
    readout_init_kernel<<<(NB * HD + 255) / 256, 256, 0, stream>>>(hsum, hmax, stats2, g[2], be[2], ss2);
    readout_kernel<<<ROBLK, 256, 0, stream>>>(P1, gid, ss2, awW, awb, hsum, hmax, NN);
    final_kernel<<<(NB * HD + 255) / 256, 256, 0, stream>>>(hsum, hmax, outW, outb, out);
}